// Round 2
// 79.687 us; speedup vs baseline: 1.0164x; 1.0164x over previous
//
#include <hip/hip_runtime.h>

#define NN 2048
#define KK 8
#define BB 32
#define TT 20

__global__ __launch_bounds__(1024) void osci_kernel(
    const float* __restrict__ coupling,   // [B,N,K]
    const float* __restrict__ phase0,     // [B,N]
    const float* __restrict__ omega,      // [B,N]
    const int*   __restrict__ conn,       // [N,K]
    float*       __restrict__ out)        // [T+1,B,N]
{
    const int b   = blockIdx.x;
    const int tid = threadIdx.x;

    // flattened double buffer: buf0 = ph_buf[0..NN), buf1 = ph_buf[NN..2NN)
    // (buf1 accesses fold to ds_read/ds_write offset:8192 immediates)
    __shared__ float ph_buf[2 * NN];

    // per-thread state: 2 oscillators each (2*1024 = 2048)
    int   cidx[2][KK];
    float w[2][KK];
    float inv_n[2];
    float om[2];
    float ph[2];

    for (int t = 0; t < 2; ++t) {
        const int i = tid + t * 1024;
        float p = phase0[b * NN + i];
        ph[t] = p;
        ph_buf[i] = p;
        out[(size_t)b * NN + i] = p;          // out[0, b, i] = phase0
        om[t] = omega[b * NN + i];

        int   jj[KK];
        float vv[KK];
        #pragma unroll
        for (int k = 0; k < KK; ++k) {
            jj[k] = conn[i * KK + k];
            vv[k] = coupling[((size_t)b * NN + i) * KK + k];
        }
        // last-wins scatter dedup: entry k vanishes if any k2>k hits same column;
        // n = count of surviving nonzero dense-row entries
        int cnt = 0;
        #pragma unroll
        for (int k = 0; k < KK; ++k) {
            bool over = false;
            #pragma unroll
            for (int k2 = k + 1; k2 < KK; ++k2) over = over || (jj[k2] == jj[k]);
            if (over) vv[k] = 0.0f;
            if (vv[k] != 0.0f) ++cnt;
        }
        #pragma unroll
        for (int k = 0; k < KK; ++k) { cidx[t][k] = jj[k]; w[t][k] = vv[k]; }
        inv_n[t] = 1.0f / (float)cnt;         // cnt >= 1 always (last write survives)
    }
    __syncthreads();   // setup: full drain once is fine

    float* outp = out + ((size_t)BB + b) * NN;   // &out[1][b][0]

    #pragma unroll 1
    for (int sp = 0; sp < TT; sp += 2) {
        // ---- even step: read buf0, write buf1 ----
        #pragma unroll
        for (int t = 0; t < 2; ++t) {
            const int i = tid + t * 1024;
            float acc = 0.0f;
            #pragma unroll
            for (int k = 0; k < KK; ++k) {
                const float pj = ph_buf[cidx[t][k]];          // ds_read offset:0
                acc += w[t][k] * __sinf(pj - ph[t]);          // bit-identical math
            }
            const float pn = ph[t] + acc * inv_n[t] + om[t];  // eps=1, ANNEAL=0
            ph[t] = pn;
            ph_buf[NN + i] = pn;                              // ds_write offset:8192
            outp[i] = pn;                                     // fire-and-forget HBM store
        }
        // LDS-only barrier: own ds_reads (WAR) + ds_writes (RAW) complete; no vmcnt drain
        asm volatile("s_waitcnt lgkmcnt(0)" ::: "memory");
        __builtin_amdgcn_s_barrier();
        asm volatile("" ::: "memory");
        outp += (size_t)BB * NN;

        // ---- odd step: read buf1, write buf0 ----
        #pragma unroll
        for (int t = 0; t < 2; ++t) {
            const int i = tid + t * 1024;
            float acc = 0.0f;
            #pragma unroll
            for (int k = 0; k < KK; ++k) {
                const float pj = ph_buf[NN + cidx[t][k]];     // ds_read offset:8192
                acc += w[t][k] * __sinf(pj - ph[t]);
            }
            const float pn = ph[t] + acc * inv_n[t] + om[t];
            ph[t] = pn;
            ph_buf[i] = pn;                                   // ds_write offset:0
            outp[i] = pn;
        }
        asm volatile("s_waitcnt lgkmcnt(0)" ::: "memory");
        __builtin_amdgcn_s_barrier();
        asm volatile("" ::: "memory");
        outp += (size_t)BB * NN;
    }
}

extern "C" void kernel_launch(void* const* d_in, const int* in_sizes, int n_in,
                              void* d_out, int out_size, void* d_ws, size_t ws_size,
                              hipStream_t stream) {
    const float* coupling = (const float*)d_in[0];   // [B,N,K]
    const float* phase0   = (const float*)d_in[1];   // [B,N]
    const float* omega    = (const float*)d_in[2];   // [B,N]
    const int*   conn     = (const int*)d_in[3];     // [N,K]
    float* out = (float*)d_out;                      // [T+1,B,N]

    osci_kernel<<<BB, 1024, 0, stream>>>(coupling, phase0, omega, conn, out);
}